// Round 1
// baseline (664.054 us; speedup 1.0000x reference)
//
#include <hip/hip_runtime.h>

// FreeConv2D: B=64,H=W=64,C=64, U=64,K=5,S=2 -> OH=OW=30
// out[b,oh,ow,u] = sum_{i,j,c} x[b,oh*2+i,ow*2+j,c] * w[oh,ow,u,i,j,c] + bias[oh,ow,u]
// One block per (oh,ow): GEMM M=64(b) x N=64(u) x K=1600, bf16 MFMA, fp32 accum.
// R1: + cross-chunk register prefetch of the w stream (HBM latency hidden under
//     A-convert + barrier + MFMA + barrier), + bijective XCD swizzle so
//     ow/oh-adjacent blocks share x via same-XCD L2, + cc/ww derived per chunk
//     (saves 20 VGPRs -> peak ~120, keeps 4 blocks/CU at launch_bounds(256,4)).
// Math order and f2bf rounding identical to R0 -> bit-identical output.

typedef __bf16 bf16x8 __attribute__((ext_vector_type(8)));
typedef float f32x4 __attribute__((ext_vector_type(4)));

__device__ __forceinline__ unsigned short f2bf(float f) {
    unsigned int u = __float_as_uint(f);
    u += 0x7FFFu + ((u >> 16) & 1u);   // round-to-nearest-even
    return (unsigned short)(u >> 16);
}

__device__ __forceinline__ ushort4 pk4(const float4 v) {
    ushort4 p;
    p.x = f2bf(v.x); p.y = f2bf(v.y); p.z = f2bf(v.z); p.w = f2bf(v.w);
    return p;
}

// LDS layout (per 160-k chunk, 64 rows), element (m,k):
//   block = (k>>5)*4 + (m>>4)          (5 k-steps x 4 row-tiles, 512 ushorts each)
//   grp   = (k>>3)&3
//   ad    = block*512 + grp*128 + ((m&15)^grp)*8 + (k&7)
// Frag read (kstep ks, tile tt), lane l: ad = (ks*4+tt)*512 + (l>>4)*128 + ((l&15)^(l>>4))*8
//   -> one contiguous ds_read_b128 per frag. Staging writes ~2-way (free).

__global__ __launch_bounds__(256, 4)
void freeconv_kernel(const float* __restrict__ x,
                     const float* __restrict__ w,
                     const float* __restrict__ bias,
                     float* __restrict__ out) {
    __shared__ __align__(16) unsigned short ldsA[10240];   // x-window chunk: 64 x 160 bf16
    __shared__ __align__(16) unsigned short ldsB[10240];   // weight chunk:   64 x 160 bf16

    // Bijective XCD-contiguous swizzle: 900 wgs over 8 XCDs (q=112, r=4).
    // xcd 0..3 own 113 consecutive bids, xcd 4..7 own 112 -> adjacent (oh,ow)
    // tiles land on the same XCD and share x columns through that XCD's L2.
    const int orig = blockIdx.x;
    const int xcd  = orig & 7;
    const int idx  = orig >> 3;
    const int bid  = (xcd < 4) ? (xcd * 113 + idx)
                               : (452 + (xcd - 4) * 112 + idx);

    const int oh = bid / 30;
    const int ow = bid - oh * 30;
    const int t = threadIdx.x;
    const int lane = t & 63;
    const int wave = t >> 6;
    const int wm = wave >> 1;   // m rows [wm*32, wm*32+32)
    const int wn = wave & 1;    // n cols [wn*32, wn*32+32)

    // read-side swizzle offset (ushorts): lane-group + XOR'd row-in-tile
    const int swz = ((lane >> 4) << 7) + (((lane & 15) ^ (lane >> 4)) << 3);

    // staging map: g = q*256 + t; row = g/40; cc = (g%40)*4 = q*1024 + 4t - row*160
    int rr[10];
#pragma unroll
    for (int q = 0; q < 10; ++q) rr[q] = (q * 256 + t) / 40;
    const int t4 = t << 2;

    f32x4 acc[2][2];
#pragma unroll
    for (int a = 0; a < 2; ++a)
#pragma unroll
        for (int b2 = 0; b2 < 2; ++b2)
#pragma unroll
            for (int r = 0; r < 4; ++r) acc[a][b2][r] = 0.f;

    const float* wblk = w + (size_t)bid * 102400;   // [64][1600] fp32, row-major

    // ---- prologue: issue w loads for chunk 0 (boff = 0) ----
    float4 vb[10];
#pragma unroll
    for (int q = 0; q < 10; ++q) {
        const int cc = q * 1024 + t4 - rr[q] * 160;
        vb[q] = *(const float4*)(wblk + rr[q] * 1600 + cc);
    }

    for (int ci = 0; ci < 10; ++ci) {
        const int i  = ci >> 1;      // kernel row 0..4
        const int kh = ci & 1;       // half of the 320-float i-slice
        const int aoff = (oh * 2 + i) * 4096 + ow * 128 + kh * 160;

        // A (x) loads for current chunk: L2/L3-resident, short latency;
        // their wait is covered by the B-convert below.
        float4 va[10];
#pragma unroll
        for (int q = 0; q < 10; ++q) {
            const int cc = q * 1024 + t4 - rr[q] * 160;
            va[q] = *(const float4*)(x + rr[q] * 262144 + aoff + cc);
        }

        // B convert + LDS write (vb holds chunk ci, prefetched last iteration)
#pragma unroll
        for (int q = 0; q < 10; ++q) {
            const int cc  = q * 1024 + t4 - rr[q] * 160;
            const int grp = (cc >> 3) & 3;
            const int wv  = ((cc >> 5) * 4 + (rr[q] >> 4)) * 512 + grp * 128
                          + (((rr[q] & 15) ^ grp) << 3) + (cc & 7);
            *(ushort4*)&ldsB[wv] = pk4(vb[q]);
        }

        // issue w loads for chunk ci+1 NOW -> in flight across A-convert,
        // barrier, MFMA phase, barrier (~700-900 cyc of cover)
        if (ci < 9) {
            const int boff2 = ((ci + 1) >> 1) * 320 + ((ci + 1) & 1) * 160;
#pragma unroll
            for (int q = 0; q < 10; ++q) {
                const int cc = q * 1024 + t4 - rr[q] * 160;
                vb[q] = *(const float4*)(wblk + rr[q] * 1600 + boff2 + cc);
            }
        }

        // A convert + LDS write
#pragma unroll
        for (int q = 0; q < 10; ++q) {
            const int cc  = q * 1024 + t4 - rr[q] * 160;
            const int grp = (cc >> 3) & 3;
            const int wv  = ((cc >> 5) * 4 + (rr[q] >> 4)) * 512 + grp * 128
                          + (((rr[q] & 15) ^ grp) << 3) + (cc & 7);
            *(ushort4*)&ldsA[wv] = pk4(va[q]);
        }

        __syncthreads();

#pragma unroll
        for (int ks = 0; ks < 5; ++ks) {
            const bf16x8 a0 = *(const bf16x8*)&ldsA[(ks * 4 + wm * 2 + 0) * 512 + swz];
            const bf16x8 a1 = *(const bf16x8*)&ldsA[(ks * 4 + wm * 2 + 1) * 512 + swz];
            const bf16x8 b0 = *(const bf16x8*)&ldsB[(ks * 4 + wn * 2 + 0) * 512 + swz];
            const bf16x8 b1 = *(const bf16x8*)&ldsB[(ks * 4 + wn * 2 + 1) * 512 + swz];
            acc[0][0] = __builtin_amdgcn_mfma_f32_16x16x32_bf16(a0, b0, acc[0][0], 0, 0, 0);
            acc[0][1] = __builtin_amdgcn_mfma_f32_16x16x32_bf16(a0, b1, acc[0][1], 0, 0, 0);
            acc[1][0] = __builtin_amdgcn_mfma_f32_16x16x32_bf16(a1, b0, acc[1][0], 0, 0, 0);
            acc[1][1] = __builtin_amdgcn_mfma_f32_16x16x32_bf16(a1, b1, acc[1][1], 0, 0, 0);
        }

        __syncthreads();
    }

    // epilogue: C/D layout col=lane&15, row=(lane>>4)*4+reg; add bias; store fp32
    const float* bp = bias + (size_t)bid * 64;
    const int col = lane & 15;
    const int r0 = (lane >> 4) * 4;
    const float bv0 = bp[wn * 32 + col];
    const float bv1 = bp[wn * 32 + 16 + col];
#pragma unroll
    for (int ms = 0; ms < 2; ++ms) {
#pragma unroll
        for (int r = 0; r < 4; ++r) {
            const int bi = wm * 32 + ms * 16 + r0 + r;      // batch index
            float* op = out + ((size_t)(bi * 30 + oh) * 30 + ow) * 64 + wn * 32 + col;
            op[0]  = acc[ms][0][r] + bv0;
            op[16] = acc[ms][1][r] + bv1;
        }
    }
}

extern "C" void kernel_launch(void* const* d_in, const int* in_sizes, int n_in,
                              void* d_out, int out_size, void* d_ws, size_t ws_size,
                              hipStream_t stream) {
    const float* x = (const float*)d_in[0];
    const float* w = (const float*)d_in[1];
    const float* b = (const float*)d_in[2];
    float* out = (float*)d_out;
    (void)in_sizes; (void)n_in; (void)out_size; (void)d_ws; (void)ws_size;
    freeconv_kernel<<<dim3(900), dim3(256), 0, stream>>>(x, w, b, out);
}

// Round 3
// 523.433 us; speedup vs baseline: 1.2687x; 1.2687x over previous
//
#include <hip/hip_runtime.h>

// FreeConv2D: B=64,H=W=64,C=64, U=64,K=5,S=2 -> OH=OW=30
// out[b,oh,ow,u] = sum_{i,j,c} x[b,oh*2+i,ow*2+j,c] * w[oh,ow,u,i,j,c] + bias[oh,ow,u]
// One block per (oh,ow): GEMM M=64(b) x N=64(u) x K=1600, bf16 MFMA, fp32 accum.
// R3 = R2 with the compile fix: __builtin_nontemporal_load needs a clang
// ext_vector pointer (f32x4), not HIP_vector_type float4.
//   - nt loads on the read-once 369MB w stream (stop it evicting the x window
//     from L2/L3; R1 counters: x re-fetched 3.2x from HBM, 215MB excess FETCH)
//   - nt stores for the write-once output
//   - bijective XCD-contiguous blockIdx swizzle (numerically no-op)
// Math order and f2bf rounding identical to R0 -> bit-identical output.

typedef __bf16 bf16x8 __attribute__((ext_vector_type(8)));
typedef float f32x4 __attribute__((ext_vector_type(4)));

__device__ __forceinline__ unsigned short f2bf(float f) {
    unsigned int u = __float_as_uint(f);
    u += 0x7FFFu + ((u >> 16) & 1u);   // round-to-nearest-even
    return (unsigned short)(u >> 16);
}

// LDS layout (per 160-k chunk, 64 rows), element (m,k):
//   block = (k>>5)*4 + (m>>4)          (5 k-steps x 4 row-tiles, 512 ushorts each)
//   grp   = (k>>3)&3
//   ad    = block*512 + grp*128 + ((m&15)^grp)*8 + (k&7)
// Frag read (kstep ks, tile tt), lane l: ad = (ks*4+tt)*512 + (l>>4)*128 + ((l&15)^(l>>4))*8
//   -> one contiguous ds_read_b128 per frag. Staging writes ~2-way (free).

__global__ __launch_bounds__(256, 4)
void freeconv_kernel(const float* __restrict__ x,
                     const float* __restrict__ w,
                     const float* __restrict__ bias,
                     float* __restrict__ out) {
    __shared__ __align__(16) unsigned short ldsA[10240];   // x-window chunk: 64 x 160 bf16
    __shared__ __align__(16) unsigned short ldsB[10240];   // weight chunk:   64 x 160 bf16

    // Bijective XCD-contiguous swizzle: 900 wgs over 8 XCDs (q=112, r=4).
    const int orig = blockIdx.x;
    const int xcd  = orig & 7;
    const int idx  = orig >> 3;
    const int bid  = (xcd < 4) ? (xcd * 113 + idx)
                               : (452 + (xcd - 4) * 112 + idx);

    const int oh = bid / 30;
    const int ow = bid - oh * 30;
    const int t = threadIdx.x;
    const int lane = t & 63;
    const int wave = t >> 6;
    const int wm = wave >> 1;   // m rows [wm*32, wm*32+32)
    const int wn = wave & 1;    // n cols [wn*32, wn*32+32)

    // read-side swizzle offset (ushorts): lane-group + XOR'd row-in-tile
    const int swz = ((lane >> 4) << 7) + (((lane & 15) ^ (lane >> 4)) << 3);

    // staging map: 2560 float4 slots per matrix per chunk; g = it*256+t
    // row = g/40 (64 rows), col = (g%40)*4 floats within the 160-float row-chunk
    int rr[10], cc[10], ww[10];
#pragma unroll
    for (int it = 0; it < 10; ++it) {
        int g = it * 256 + t;
        int r = g / 40;
        int k = (g - r * 40) * 4;
        rr[it] = r;
        cc[it] = k;
        int grp = (k >> 3) & 3;
        ww[it] = ((k >> 5) * 4 + (r >> 4)) * 512 + grp * 128 + (((r & 15) ^ grp) * 8) + (k & 7);
    }

    f32x4 acc[2][2];
#pragma unroll
    for (int a = 0; a < 2; ++a)
#pragma unroll
        for (int b2 = 0; b2 < 2; ++b2)
#pragma unroll
            for (int r = 0; r < 4; ++r) acc[a][b2][r] = 0.f;

    const float* wblk = w + (size_t)bid * 102400;   // [64][1600] fp32, row-major

    for (int ci = 0; ci < 10; ++ci) {
        const int i  = ci >> 1;      // kernel row 0..4
        const int kh = ci & 1;       // half of the 320-float i-slice
        const int aoff = (oh * 2 + i) * 4096 + ow * 128 + kh * 160;  // floats into x (plus b*262144)
        const int boff = i * 320 + kh * 160;                          // floats into w row

#pragma unroll
        for (int bt = 0; bt < 2; ++bt) {
            float4 va[5];
            f32x4 vb[5];
#pragma unroll
            for (int q = 0; q < 5; ++q) {
                int it = bt * 5 + q;
                va[q] = *(const float4*)(x + rr[it] * 262144 + aoff + cc[it]);
            }
#pragma unroll
            for (int q = 0; q < 5; ++q) {
                int it = bt * 5 + q;
                // w is read-once: non-temporal, don't evict the x window from L2/L3
                vb[q] = __builtin_nontemporal_load(
                            (const f32x4*)(wblk + rr[it] * 1600 + boff + cc[it]));
            }
#pragma unroll
            for (int q = 0; q < 5; ++q) {
                int it = bt * 5 + q;
                ushort4 pv;
                pv.x = f2bf(va[q].x); pv.y = f2bf(va[q].y);
                pv.z = f2bf(va[q].z); pv.w = f2bf(va[q].w);
                *(ushort4*)&ldsA[ww[it]] = pv;
            }
#pragma unroll
            for (int q = 0; q < 5; ++q) {
                int it = bt * 5 + q;
                ushort4 pv;
                pv.x = f2bf(vb[q][0]); pv.y = f2bf(vb[q][1]);
                pv.z = f2bf(vb[q][2]); pv.w = f2bf(vb[q][3]);
                *(ushort4*)&ldsB[ww[it]] = pv;
            }
        }
        __syncthreads();

#pragma unroll
        for (int ks = 0; ks < 5; ++ks) {
            const bf16x8 a0 = *(const bf16x8*)&ldsA[(ks * 4 + wm * 2 + 0) * 512 + swz];
            const bf16x8 a1 = *(const bf16x8*)&ldsA[(ks * 4 + wm * 2 + 1) * 512 + swz];
            const bf16x8 b0 = *(const bf16x8*)&ldsB[(ks * 4 + wn * 2 + 0) * 512 + swz];
            const bf16x8 b1 = *(const bf16x8*)&ldsB[(ks * 4 + wn * 2 + 1) * 512 + swz];
            acc[0][0] = __builtin_amdgcn_mfma_f32_16x16x32_bf16(a0, b0, acc[0][0], 0, 0, 0);
            acc[0][1] = __builtin_amdgcn_mfma_f32_16x16x32_bf16(a0, b1, acc[0][1], 0, 0, 0);
            acc[1][0] = __builtin_amdgcn_mfma_f32_16x16x32_bf16(a1, b0, acc[1][0], 0, 0, 0);
            acc[1][1] = __builtin_amdgcn_mfma_f32_16x16x32_bf16(a1, b1, acc[1][1], 0, 0, 0);
        }
        __syncthreads();
    }

    // epilogue: C/D layout col=lane&15, row=(lane>>4)*4+reg; add bias; store fp32
    const float* bp = bias + (size_t)bid * 64;
    const int col = lane & 15;
    const int r0 = (lane >> 4) * 4;
    const float bv0 = bp[wn * 32 + col];
    const float bv1 = bp[wn * 32 + 16 + col];
#pragma unroll
    for (int ms = 0; ms < 2; ++ms) {
#pragma unroll
        for (int r = 0; r < 4; ++r) {
            const int bi = wm * 32 + ms * 16 + r0 + r;      // batch index
            float* op = out + ((size_t)(bi * 30 + oh) * 30 + ow) * 64 + wn * 32 + col;
            __builtin_nontemporal_store(acc[ms][0][r] + bv0, op);
            __builtin_nontemporal_store(acc[ms][1][r] + bv1, op + 16);
        }
    }
}

extern "C" void kernel_launch(void* const* d_in, const int* in_sizes, int n_in,
                              void* d_out, int out_size, void* d_ws, size_t ws_size,
                              hipStream_t stream) {
    const float* x = (const float*)d_in[0];
    const float* w = (const float*)d_in[1];
    const float* b = (const float*)d_in[2];
    float* out = (float*)d_out;
    (void)in_sizes; (void)n_in; (void)out_size; (void)d_ws; (void)ws_size;
    freeconv_kernel<<<dim3(900), dim3(256), 0, stream>>>(x, w, b, out);
}